// Round 1
// baseline (821.634 us; speedup 1.0000x reference)
//
#include <hip/hip_runtime.h>

// ---------------------------------------------------------------------------
// MixtralAttention on MI355X (gfx950)
// B=2, S=2048, HID=4096, NH=32, NKV=8, HD=128, WINDOW=1024, THETA=10000
// Stages: cvt(+T) -> GEMM1(qkv) -> RoPE -> flash attn -> GEMM2(out)
// All matmuls: bf16 MFMA 16x16x32, m97-style 128x128 tile, B^T operand.
// ---------------------------------------------------------------------------

typedef __attribute__((ext_vector_type(8))) short short8;       // bf16x8 frag
typedef __attribute__((ext_vector_type(4))) float f32x4;        // MFMA acc
typedef __attribute__((ext_vector_type(4))) unsigned int u32x4; // 16B load
typedef __attribute__((ext_vector_type(4))) unsigned short u16x4;

__device__ __forceinline__ unsigned short f2bf(float f) {
  unsigned int u = __builtin_bit_cast(unsigned int, f);
  u = u + 0x7fffu + ((u >> 16) & 1u);   // round-to-nearest-even
  return (unsigned short)(u >> 16);
}
__device__ __forceinline__ float bf2f(unsigned short h) {
  unsigned int u = ((unsigned int)h) << 16;
  return __builtin_bit_cast(float, u);
}

__device__ __forceinline__ void gload_lds16(const unsigned short* g, unsigned short* l) {
  __builtin_amdgcn_global_load_lds(
      (const __attribute__((address_space(1))) unsigned int*)g,
      (__attribute__((address_space(3))) unsigned int*)l, 16, 0, 0);
}

#define MFMA16(A, B, C) __builtin_amdgcn_mfma_f32_16x16x32_bf16((A), (B), (C), 0, 0, 0)

// ---------------------------------------------------------------------------
// fp32 -> bf16 plain convert (n divisible by 1024)
// ---------------------------------------------------------------------------
__global__ __launch_bounds__(256) void cvt_plain(const float* __restrict__ in,
                                                 unsigned short* __restrict__ out, int n) {
  const int i = (blockIdx.x * 256 + threadIdx.x) * 4;
  f32x4 v = *(const f32x4*)(in + i);
  u16x4 o;
#pragma unroll
  for (int j = 0; j < 4; ++j) o[j] = f2bf(v[j]);
  *(u16x4*)(out + i) = o;
}

// ---------------------------------------------------------------------------
// fp32 [R][C] -> bf16 transposed [C][R]   (R,C divisible by 32)
// ---------------------------------------------------------------------------
__global__ __launch_bounds__(256) void cvt_t(const float* __restrict__ in,
                                             unsigned short* __restrict__ out,
                                             int R, int C) {
  __shared__ float t[32][33];
  const int c0 = blockIdx.x * 32, r0 = blockIdx.y * 32;
  const int tx = threadIdx.x & 31, ty = threadIdx.x >> 5;  // ty: 0..7
#pragma unroll
  for (int i = 0; i < 4; ++i)
    t[ty + i * 8][tx] = in[(size_t)(r0 + ty + i * 8) * C + c0 + tx];
  __syncthreads();
#pragma unroll
  for (int i = 0; i < 4; ++i)
    out[(size_t)(c0 + ty + i * 8) * R + r0 + tx] = f2bf(t[tx][ty + i * 8]);
}

// ---------------------------------------------------------------------------
// GEMM: C[M,N] = A[M,K] * B^T[N,K]   (bf16 in, fp32 acc; out bf16 or fp32)
// 128x128 tile, BK=32, 256 threads (4 waves, 2x2), 4x4 16x16x32 frags/wave.
// global_load_lds width-16 staging (m97 structure). M,N,K divisible by 128.
// ---------------------------------------------------------------------------
template <int OUTF32>
__global__ __launch_bounds__(256) void gemm_bt(const unsigned short* __restrict__ A,
                                               const unsigned short* __restrict__ BT,
                                               void* __restrict__ Cout,
                                               int M, int N, int K) {
  __shared__ __align__(16) unsigned short As[128 * 32];
  __shared__ __align__(16) unsigned short Bs[128 * 32];
  const int tid = threadIdx.x;
  const int lane = tid & 63;
  const int w = tid >> 6;          // wave 0..3
  const int wr = w >> 1, wc = w & 1;
  const int g = lane >> 4;         // 0..3
  const int l15 = lane & 15;
  const int m0 = blockIdx.x * 128;
  const int n0 = blockIdx.y * 128;

  const int srow = lane >> 2;       // 0..15 (staging row within chunk)
  const int scol = (lane & 3) * 8;  // 0,8,16,24 (bf16 col)

  f32x4 acc[4][4] = {};

  const unsigned short* Abase = A + (size_t)(m0 + srow) * K + scol;
  const unsigned short* Bbase = BT + (size_t)(n0 + srow) * K + scol;

  const int nkt = K >> 5;
  for (int kt = 0; kt < nkt; ++kt) {
    const int kof = kt * 32;
    // stage A-tile [128][32] and BT-tile [128][32] (linear LDS, 1KB per instr)
#pragma unroll
    for (int i = 0; i < 2; ++i) {
      const int c = w * 2 + i;   // chunk 0..7 -> rows [c*16, c*16+16)
      gload_lds16(Abase + (size_t)(c * 16) * K + kof, &As[c * 512]);
      gload_lds16(Bbase + (size_t)(c * 16) * K + kof, &Bs[c * 512]);
    }
    __syncthreads();   // drains vmcnt (global_load_lds) then barrier

    u32x4 af[4], bfr[4];
#pragma unroll
    for (int mi = 0; mi < 4; ++mi)
      af[mi] = *(const u32x4*)&As[(wr * 64 + mi * 16 + l15) * 32 + g * 8];
#pragma unroll
    for (int ni = 0; ni < 4; ++ni)
      bfr[ni] = *(const u32x4*)&Bs[(wc * 64 + ni * 16 + l15) * 32 + g * 8];
#pragma unroll
    for (int mi = 0; mi < 4; ++mi)
#pragma unroll
      for (int ni = 0; ni < 4; ++ni)
        acc[mi][ni] = MFMA16(__builtin_bit_cast(short8, af[mi]),
                             __builtin_bit_cast(short8, bfr[ni]), acc[mi][ni]);
    __syncthreads();
  }

  // epilogue: C row = (lane>>4)*4 + r, col = lane&15 (m89-verified layout)
  const int crow0 = m0 + wr * 64;
  const int ccol0 = n0 + wc * 64;
#pragma unroll
  for (int mi = 0; mi < 4; ++mi)
#pragma unroll
    for (int ni = 0; ni < 4; ++ni)
#pragma unroll
      for (int r = 0; r < 4; ++r) {
        const size_t idx =
            (size_t)(crow0 + mi * 16 + g * 4 + r) * N + (ccol0 + ni * 16 + l15);
        if constexpr (OUTF32) ((float*)Cout)[idx] = acc[mi][ni][r];
        else ((unsigned short*)Cout)[idx] = f2bf(acc[mi][ni][r]);
      }
}

// ---------------------------------------------------------------------------
// RoPE (NeoX): in-place on qkv bf16 [B*S][6144]; heads 0..31 = Q, 32..39 = K.
// one thread per (token, head, d<64) pair.
// ---------------------------------------------------------------------------
__global__ __launch_bounds__(256) void rope_kernel(unsigned short* __restrict__ qkv,
                                                   const int* __restrict__ pos) {
  const int idx = blockIdx.x * 256 + threadIdx.x;   // < 4096*40*64
  const int d = idx & 63;
  const int hh = (idx >> 6) % 40;
  const int tok = idx / 2560;       // 64*40
  const int s = tok & 2047;
  const int off = (hh < 32) ? hh * 128 : 4096 + (hh - 32) * 128;
  unsigned short* p = qkv + (size_t)tok * 6144 + off + d;
  const float x1 = bf2f(p[0]);
  const float x2 = bf2f(p[64]);
  // inv_freq = 10000^(-d/64) = 2^(-d*log2(10000)/64)
  const float inv = exp2f(-(float)d * 0.2076205059304601f);
  const float ang = (float)pos[s] * inv;
  const float c = cosf(ang), sn = sinf(ang);
  p[0]  = f2bf(x1 * c - x2 * sn);
  p[64] = f2bf(x2 * c + x1 * sn);
}

// ---------------------------------------------------------------------------
// Flash attention, GQA, causal + sliding window 1024.
// grid: (S/64, NH, B); block: 256 (4 waves, 16 q-rows each). KV tile = 32.
// Swapped QK^T (mfma(K, Q^T)) so each lane owns one q-row's scores.
// V stored transposed in LDS so PV B-frags are contiguous b128 reads.
// ---------------------------------------------------------------------------
__global__ __launch_bounds__(256) void attn_kernel(const unsigned short* __restrict__ qkv,
                                                   unsigned short* __restrict__ aout) {
  __shared__ __align__(16) unsigned short k_lds[32 * 136];  // [key][128+8]
  __shared__ __align__(16) unsigned short v_lds[128 * 40];  // [d][32+8] = V^T

  const int tid = threadIdx.x;
  const int lane = tid & 63;
  const int w = tid >> 6;
  const int g = lane >> 4;
  const int q15 = lane & 15;
  const int q0 = blockIdx.x * 64;
  const int h = blockIdx.y;
  const int b = blockIdx.z;
  const int kh = h >> 2;            // NH/NKV = 4
  const size_t tokbase = (size_t)b * 2048;

  const int qrow = q0 + w * 16 + q15;   // this lane's q-row (for scores)

  // Q fragments (B-operand of swapped QK^T): lane holds Q[q15-row][ks*32+g*8 ..+7]
  u32x4 qf[4];
  {
    const unsigned short* qp = qkv + (tokbase + qrow) * 6144 + h * 128;
#pragma unroll
    for (int ks = 0; ks < 4; ++ks)
      qf[ks] = *(const u32x4*)(qp + ks * 32 + g * 8);
  }

  float m_run = -1e30f, l_run = 0.0f;
  f32x4 o_acc[8] = {};   // O[q=g*4+r][d=nb*16+q15]

  int lo = q0 - 1023; if (lo < 0) lo = 0;
  const int t_lo = lo >> 5;
  const int t_hi = (q0 + 63) >> 5;

  const int srow = tid >> 3;          // 0..31 staging key-row
  const int scol = (tid & 7) * 16;    // 0..112 staging d-col

  for (int kt = t_lo; kt <= t_hi; ++kt) {
    __syncthreads();
    {  // stage K (row-major, +8 pad) and V^T
      const size_t ktok = tokbase + kt * 32 + srow;
      const unsigned short* kp = qkv + ktok * 6144 + 4096 + kh * 128 + scol;
      const unsigned short* vp = kp + 1024;   // V right after K
      u32x4 k0 = *(const u32x4*)kp;
      u32x4 k1 = *(const u32x4*)(kp + 8);
      u32x4 v0 = *(const u32x4*)vp;
      u32x4 v1 = *(const u32x4*)(vp + 8);
      *(u32x4*)&k_lds[srow * 136 + scol] = k0;
      *(u32x4*)&k_lds[srow * 136 + scol + 8] = k1;
      union { u32x4 v[2]; unsigned short s[16]; } vv;
      vv.v[0] = v0; vv.v[1] = v1;
#pragma unroll
      for (int e = 0; e < 16; ++e)
        v_lds[(scol + e) * 40 + srow] = vv.s[e];
    }
    __syncthreads();

    // S^T = K * Q^T : lane holds S[key = t2*16 + g*4 + r][q = q15]
    f32x4 st0 = {0.f, 0.f, 0.f, 0.f}, st1 = {0.f, 0.f, 0.f, 0.f};
#pragma unroll
    for (int ks = 0; ks < 4; ++ks) {
      u32x4 kf0 = *(const u32x4*)&k_lds[(q15)*136 + ks * 32 + g * 8];
      u32x4 kf1 = *(const u32x4*)&k_lds[(16 + q15) * 136 + ks * 32 + g * 8];
      st0 = MFMA16(__builtin_bit_cast(short8, kf0), __builtin_bit_cast(short8, qf[ks]), st0);
      st1 = MFMA16(__builtin_bit_cast(short8, kf1), __builtin_bit_cast(short8, qf[ks]), st1);
    }

    // mask + online softmax (per q-row = q15, reduce over g via shfl_xor)
    float p0[4], p1[4];
    float tm = -1e30f;
#pragma unroll
    for (int r = 0; r < 4; ++r) {
      const int key0 = kt * 32 + g * 4 + r;
      const int key1 = key0 + 16;
      float s0 = st0[r] * 0.08838834764831845f;
      float s1 = st1[r] * 0.08838834764831845f;
      s0 = (key0 <= qrow && qrow - key0 < 1024) ? s0 : -1e30f;
      s1 = (key1 <= qrow && qrow - key1 < 1024) ? s1 : -1e30f;
      p0[r] = s0; p1[r] = s1;
      tm = fmaxf(tm, fmaxf(s0, s1));
    }
    tm = fmaxf(tm, __shfl_xor(tm, 16, 64));
    tm = fmaxf(tm, __shfl_xor(tm, 32, 64));
    const float mn = fmaxf(m_run, tm);
    const float scl = __expf(m_run - mn);
    float rsum = 0.f;
#pragma unroll
    for (int r = 0; r < 4; ++r) {
      p0[r] = __expf(p0[r] - mn);
      p1[r] = __expf(p1[r] - mn);
      rsum += p0[r] + p1[r];
    }
    rsum += __shfl_xor(rsum, 16, 64);
    rsum += __shfl_xor(rsum, 32, 64);
    l_run = l_run * scl + rsum;
    m_run = mn;

    // rescale O: row q-index of o_acc is g*4+r -> fetch that row's scale
    float rs[4];
#pragma unroll
    for (int r = 0; r < 4; ++r) rs[r] = __shfl(scl, g * 4 + r, 64);
#pragma unroll
    for (int nb = 0; nb < 8; ++nb) {
      o_acc[nb][0] *= rs[0]; o_acc[nb][1] *= rs[1];
      o_acc[nb][2] *= rs[2]; o_acc[nb][3] *= rs[3];
    }

    // redistribute P into PV A-frag: lane needs P[q15][key_local = g*8 + j]
    union { unsigned short s[8]; u32x4 v; } pau;
#pragma unroll
    for (int j = 0; j < 8; ++j) {
      const int r = j & 3;
      const int srcl = q15 + 16 * (2 * (g & 1) + (j >> 2));
      const float v0 = __shfl(p0[r], srcl, 64);
      const float v1 = __shfl(p1[r], srcl, 64);
      pau.s[j] = f2bf((g >> 1) ? v1 : v0);
    }
    const short8 pa = __builtin_bit_cast(short8, pau.v);

    // O += P * V  (B-frag = V^T rows, contiguous keys)
#pragma unroll
    for (int nb = 0; nb < 8; ++nb) {
      u32x4 vf = *(const u32x4*)&v_lds[(nb * 16 + q15) * 40 + g * 8];
      o_acc[nb] = MFMA16(pa, __builtin_bit_cast(short8, vf), o_acc[nb]);
    }
  }

  // epilogue: divide by l and store bf16 [B*S][4096]
  float rl[4];
#pragma unroll
  for (int r = 0; r < 4; ++r) rl[r] = 1.0f / __shfl(l_run, g * 4 + r, 64);
#pragma unroll
  for (int nb = 0; nb < 8; ++nb)
#pragma unroll
    for (int r = 0; r < 4; ++r) {
      const int orow = q0 + w * 16 + g * 4 + r;
      aout[(tokbase + orow) * 4096 + h * 128 + nb * 16 + q15] =
          f2bf(o_acc[nb][r] * rl[r]);
    }
}

// ---------------------------------------------------------------------------
// launch
// ---------------------------------------------------------------------------
extern "C" void kernel_launch(void* const* d_in, const int* in_sizes, int n_in,
                              void* d_out, int out_size, void* d_ws, size_t ws_size,
                              hipStream_t stream) {
  (void)in_sizes; (void)n_in; (void)out_size; (void)ws_size;
  const float* hs   = (const float*)d_in[0];   // [2,2048,4096]
  const float* wqkv = (const float*)d_in[1];   // [4096,6144]
  const float* wo   = (const float*)d_in[2];   // [4096,4096]
  const int*   pos  = (const int*)d_in[3];     // [2048]
  float* out = (float*)d_out;                  // [2,2048,4096] fp32

  // workspace layout (128 MiB total, with reuse):
  //  [0, 50331648)            qkv bf16 [4096][6144]
  //  [50331648, 100663296)    wqkvT bf16 [6144][4096], later woT [4096][4096]
  //  [100663296, 134217728)   hidden bf16 [4096][4096], later attn-out bf16
  char* ws = (char*)d_ws;
  unsigned short* qkvb = (unsigned short*)ws;
  unsigned short* wT   = (unsigned short*)(ws + 50331648);
  unsigned short* hsb  = (unsigned short*)(ws + 100663296);

  // 1. convert + transpose wqkv -> wqkvT bf16 [6144][4096]
  cvt_t<<<dim3(6144 / 32, 4096 / 32), 256, 0, stream>>>(wqkv, wT, 4096, 6144);
  // 2. convert hidden -> bf16
  cvt_plain<<<16384, 256, 0, stream>>>(hs, hsb, 16777216);
  // 3. qkv = hs @ wqkv   (bf16 out)
  gemm_bt<0><<<dim3(32, 48), 256, 0, stream>>>(hsb, wT, qkvb, 4096, 6144, 4096);
  // 4. RoPE on q,k in place
  rope_kernel<<<40960, 256, 0, stream>>>(qkvb, pos);
  // 5. convert + transpose wo -> woT bf16 [4096][4096] (overwrites wqkvT)
  cvt_t<<<dim3(4096 / 32, 4096 / 32), 256, 0, stream>>>(wo, wT, 4096, 4096);
  // 6. flash attention -> attn bf16 (reuses hidden-bf16 region)
  attn_kernel<<<dim3(32, 32, 2), 256, 0, stream>>>(qkvb, hsb);
  // 7. out = attn @ wo  (fp32 out)
  gemm_bt<1><<<dim3(32, 32), 256, 0, stream>>>(hsb, wT, out, 4096, 4096, 4096);
}

// Round 2
// 651.977 us; speedup vs baseline: 1.2602x; 1.2602x over previous
//
#include <hip/hip_runtime.h>

// ---------------------------------------------------------------------------
// MixtralAttention on MI355X (gfx950)
// B=2, S=2048, HID=4096, NH=32, NKV=8, HD=128, WINDOW=1024, THETA=10000
// Stages: cvt(+T) -> GEMM1(qkv) -> RoPE -> flash attn (8-wave 32x32 swapped)
//         -> GEMM2(out)
// ---------------------------------------------------------------------------

typedef __attribute__((ext_vector_type(8))) short short8;       // bf16x8 frag
typedef __attribute__((ext_vector_type(4))) float f32x4;        // 16x16 acc
typedef __attribute__((ext_vector_type(16))) float f32x16;      // 32x32 acc
typedef __attribute__((ext_vector_type(4))) unsigned int u32x4; // 16B load
typedef __attribute__((ext_vector_type(4))) unsigned short u16x4;

__device__ __forceinline__ unsigned short f2bf(float f) {
  unsigned int u = __builtin_bit_cast(unsigned int, f);
  u = u + 0x7fffu + ((u >> 16) & 1u);   // round-to-nearest-even
  return (unsigned short)(u >> 16);
}
__device__ __forceinline__ float bf2f(unsigned short h) {
  unsigned int u = ((unsigned int)h) << 16;
  return __builtin_bit_cast(float, u);
}
__device__ __forceinline__ unsigned int cvtpk_bf16(float lo, float hi) {
  unsigned int r;
  asm("v_cvt_pk_bf16_f32 %0, %1, %2" : "=v"(r) : "v"(lo), "v"(hi));
  return r;
}

__device__ __forceinline__ void gload_lds16(const unsigned short* g, unsigned short* l) {
  __builtin_amdgcn_global_load_lds(
      (const __attribute__((address_space(1))) unsigned int*)g,
      (__attribute__((address_space(3))) unsigned int*)l, 16, 0, 0);
}

#define MFMA16(A, B, C) __builtin_amdgcn_mfma_f32_16x16x32_bf16((A), (B), (C), 0, 0, 0)
#define MFMA32(A, B, C) __builtin_amdgcn_mfma_f32_32x32x16_bf16((A), (B), (C), 0, 0, 0)
#define BC8(x) __builtin_bit_cast(short8, (x))

// ---------------------------------------------------------------------------
// fp32 -> bf16 plain convert
// ---------------------------------------------------------------------------
__global__ __launch_bounds__(256) void cvt_plain(const float* __restrict__ in,
                                                 unsigned short* __restrict__ out, int n) {
  const int i = (blockIdx.x * 256 + threadIdx.x) * 4;
  (void)n;
  f32x4 v = *(const f32x4*)(in + i);
  u16x4 o;
#pragma unroll
  for (int j = 0; j < 4; ++j) o[j] = f2bf(v[j]);
  *(u16x4*)(out + i) = o;
}

// ---------------------------------------------------------------------------
// fp32 [R][C] -> bf16 transposed [C][R]
// ---------------------------------------------------------------------------
__global__ __launch_bounds__(256) void cvt_t(const float* __restrict__ in,
                                             unsigned short* __restrict__ out,
                                             int R, int C) {
  __shared__ float t[32][33];
  const int c0 = blockIdx.x * 32, r0 = blockIdx.y * 32;
  const int tx = threadIdx.x & 31, ty = threadIdx.x >> 5;
#pragma unroll
  for (int i = 0; i < 4; ++i)
    t[ty + i * 8][tx] = in[(size_t)(r0 + ty + i * 8) * C + c0 + tx];
  __syncthreads();
#pragma unroll
  for (int i = 0; i < 4; ++i)
    out[(size_t)(c0 + ty + i * 8) * R + r0 + tx] = f2bf(t[tx][ty + i * 8]);
}

// ---------------------------------------------------------------------------
// GEMM: C[M,N] = A[M,K] * B^T[N,K]  (m97 structure, unchanged this round)
// ---------------------------------------------------------------------------
template <int OUTF32>
__global__ __launch_bounds__(256) void gemm_bt(const unsigned short* __restrict__ A,
                                               const unsigned short* __restrict__ BT,
                                               void* __restrict__ Cout,
                                               int M, int N, int K) {
  __shared__ __align__(16) unsigned short As[128 * 32];
  __shared__ __align__(16) unsigned short Bs[128 * 32];
  const int tid = threadIdx.x;
  const int lane = tid & 63;
  const int w = tid >> 6;
  const int wr = w >> 1, wc = w & 1;
  const int g = lane >> 4;
  const int l15 = lane & 15;
  const int m0 = blockIdx.x * 128;
  const int n0 = blockIdx.y * 128;

  const int srow = lane >> 2;
  const int scol = (lane & 3) * 8;

  f32x4 acc[4][4] = {};

  const unsigned short* Abase = A + (size_t)(m0 + srow) * K + scol;
  const unsigned short* Bbase = BT + (size_t)(n0 + srow) * K + scol;

  const int nkt = K >> 5;
  for (int kt = 0; kt < nkt; ++kt) {
    const int kof = kt * 32;
#pragma unroll
    for (int i = 0; i < 2; ++i) {
      const int c = w * 2 + i;
      gload_lds16(Abase + (size_t)(c * 16) * K + kof, &As[c * 512]);
      gload_lds16(Bbase + (size_t)(c * 16) * K + kof, &Bs[c * 512]);
    }
    __syncthreads();

    u32x4 af[4], bfr[4];
#pragma unroll
    for (int mi = 0; mi < 4; ++mi)
      af[mi] = *(const u32x4*)&As[(wr * 64 + mi * 16 + l15) * 32 + g * 8];
#pragma unroll
    for (int ni = 0; ni < 4; ++ni)
      bfr[ni] = *(const u32x4*)&Bs[(wc * 64 + ni * 16 + l15) * 32 + g * 8];
#pragma unroll
    for (int mi = 0; mi < 4; ++mi)
#pragma unroll
      for (int ni = 0; ni < 4; ++ni)
        acc[mi][ni] = MFMA16(BC8(af[mi]), BC8(bfr[ni]), acc[mi][ni]);
    __syncthreads();
  }

  const int crow0 = m0 + wr * 64;
  const int ccol0 = n0 + wc * 64;
#pragma unroll
  for (int mi = 0; mi < 4; ++mi)
#pragma unroll
    for (int ni = 0; ni < 4; ++ni)
#pragma unroll
      for (int r = 0; r < 4; ++r) {
        const size_t idx =
            (size_t)(crow0 + mi * 16 + g * 4 + r) * N + (ccol0 + ni * 16 + l15);
        if constexpr (OUTF32) ((float*)Cout)[idx] = acc[mi][ni][r];
        else ((unsigned short*)Cout)[idx] = f2bf(acc[mi][ni][r]);
      }
}

// ---------------------------------------------------------------------------
// RoPE (NeoX) in-place on qkv bf16 [4096][6144]
// ---------------------------------------------------------------------------
__global__ __launch_bounds__(256) void rope_kernel(unsigned short* __restrict__ qkv,
                                                   const int* __restrict__ pos) {
  const int idx = blockIdx.x * 256 + threadIdx.x;
  const int d = idx & 63;
  const int hh = (idx >> 6) % 40;
  const int tok = idx / 2560;
  const int s = tok & 2047;
  const int off = (hh < 32) ? hh * 128 : 4096 + (hh - 32) * 128;
  unsigned short* p = qkv + (size_t)tok * 6144 + off + d;
  const float x1 = bf2f(p[0]);
  const float x2 = bf2f(p[64]);
  const float inv = exp2f(-(float)d * 0.2076205059304601f);
  const float ang = (float)pos[s] * inv;
  const float c = cosf(ang), sn = sinf(ang);
  p[0]  = f2bf(x1 * c - x2 * sn);
  p[64] = f2bf(x2 * c + x1 * sn);
}

// ---------------------------------------------------------------------------
// Flash attention, GQA, causal + sliding window 1024.
// 8 waves x 32 q-rows (512 thr); KV tile 64, double-buffered LDS.
// Swapped QK^T: S^T = mfma32(K, Q^T) -> lane owns scores for q = lane&31.
// Swapped PV:   O^T = mfma32(V^T, P^T) -> lane owns O row q = lane&31.
// P^T frags built with v_cvt_pk_bf16_f32 + permlane32_swap (T12).
// Defer-max rescale, THR=8 (T13).
// ---------------------------------------------------------------------------
__global__ __launch_bounds__(512, 2) void attn_kernel(const unsigned short* __restrict__ qkv,
                                                      unsigned short* __restrict__ aout) {
  // per buffer: K [64][136] = 8704 elems, V^T [128][72] = 9216 elems
  __shared__ __align__(16) unsigned short smem[35840];   // 2 buffers, 70 KiB

  const int tid = threadIdx.x;
  const int lane = tid & 63;
  const int w = tid >> 6;            // wave 0..7
  const int hi = lane >> 5;          // half of wave
  const int l31 = lane & 31;
  const int q0 = blockIdx.x * 256;
  const int h = blockIdx.y;
  const int b = blockIdx.z;
  const int kh = h >> 2;             // NH/NKV = 4
  const size_t tokbase = (size_t)b * 2048;
  const int qw0 = q0 + w * 32;
  const int qg = qw0 + l31;          // this lane's q row

  // ---- Q fragments in registers (B-operand of swapped QK^T) ----
  short8 qf[8];
  {
    const unsigned short* qp = qkv + (tokbase + qg) * 6144 + h * 128;
#pragma unroll
    for (int ks8 = 0; ks8 < 8; ++ks8)
      qf[ks8] = BC8(*(const u32x4*)(qp + ks8 * 16 + hi * 8));
  }

  // ---- staging assignment: chunks c = tid, tid+512 (16B each) ----
  const int c0key = tid >> 4, c0col = tid & 15;          // chunk tid
  const int c1key = (tid + 512) >> 4, c1col = tid & 15;  // chunk tid+512

  u32x4 kreg[2], vreg[2];
  const unsigned short* kvK = qkv + tokbase * 6144 + 4096 + kh * 128;

  const int t0 = (q0 >= 1024 ? (q0 - 1023) >> 6 : 0);
  const int t1 = (q0 + 255) >> 6;

  // prologue: load+write tile t0, prefetch t0+1
  {
    const unsigned short* kb = kvK + (size_t)(t0 * 64) * 6144;
    kreg[0] = *(const u32x4*)(kb + (size_t)c0key * 6144 + c0col * 8);
    kreg[1] = *(const u32x4*)(kb + (size_t)c1key * 6144 + c1col * 8);
    vreg[0] = *(const u32x4*)(kb + (size_t)c0key * 6144 + 1024 + c0col * 8);
    vreg[1] = *(const u32x4*)(kb + (size_t)c1key * 6144 + 1024 + c1col * 8);
  }

  float m_run = -1e30f, l_run = 0.0f;
  f32x16 o_acc[4] = {};

  for (int kt = t0; kt <= t1; ++kt) {
    const int cur = (kt - t0) & 1;
    unsigned short* kdst = &smem[(cur)*17920];
    unsigned short* vdst = kdst + 8704;

    // write KV(kt==t0 ? t0 : kt+... ) -- regs currently hold KV(kt) on first
    // iter, KV(kt+1) afterwards. Unify: on iter kt, regs hold tile (kt==t0 ?
    // kt : kt+1). Write target: that tile's buffer.
    if (kt == t0) {
      // write KV(t0) into buf0
      *(u32x4*)&kdst[c0key * 136 + c0col * 8] = kreg[0];
      *(u32x4*)&kdst[c1key * 136 + c1col * 8] = kreg[1];
#pragma unroll
      for (int e = 0; e < 8; ++e) {
        const int e0 = (e + c0col) & 7;
        const int e1 = (e + c1col) & 7;
        vdst[(c0col * 8 + e0) * 72 + c0key] =
            (unsigned short)(vreg[0][e0 >> 1] >> ((e0 & 1) * 16));
        vdst[(c1col * 8 + e1) * 72 + c1key] =
            (unsigned short)(vreg[1][e1 >> 1] >> ((e1 & 1) * 16));
      }
      if (kt < t1) {   // prefetch t0+1
        const unsigned short* kb = kvK + (size_t)((kt + 1) * 64) * 6144;
        kreg[0] = *(const u32x4*)(kb + (size_t)c0key * 6144 + c0col * 8);
        kreg[1] = *(const u32x4*)(kb + (size_t)c1key * 6144 + c1col * 8);
        vreg[0] = *(const u32x4*)(kb + (size_t)c0key * 6144 + 1024 + c0col * 8);
        vreg[1] = *(const u32x4*)(kb + (size_t)c1key * 6144 + 1024 + c1col * 8);
      }
      __syncthreads();
    }

    // write KV(kt+1) into alt buffer (overlaps compute of kt)
    if (kt < t1) {
      unsigned short* kdn = &smem[(cur ^ 1) * 17920];
      unsigned short* vdn = kdn + 8704;
      *(u32x4*)&kdn[c0key * 136 + c0col * 8] = kreg[0];
      *(u32x4*)&kdn[c1key * 136 + c1col * 8] = kreg[1];
#pragma unroll
      for (int e = 0; e < 8; ++e) {
        const int e0 = (e + c0col) & 7;
        const int e1 = (e + c1col) & 7;
        vdn[(c0col * 8 + e0) * 72 + c0key] =
            (unsigned short)(vreg[0][e0 >> 1] >> ((e0 & 1) * 16));
        vdn[(c1col * 8 + e1) * 72 + c1key] =
            (unsigned short)(vreg[1][e1 >> 1] >> ((e1 & 1) * 16));
      }
      if (kt + 2 <= t1) {   // prefetch tile kt+2 into regs
        const unsigned short* kb = kvK + (size_t)((kt + 2) * 64) * 6144;
        kreg[0] = *(const u32x4*)(kb + (size_t)c0key * 6144 + c0col * 8);
        kreg[1] = *(const u32x4*)(kb + (size_t)c1key * 6144 + c1col * 8);
        vreg[0] = *(const u32x4*)(kb + (size_t)c0key * 6144 + 1024 + c0col * 8);
        vreg[1] = *(const u32x4*)(kb + (size_t)c1key * 6144 + 1024 + c1col * 8);
      }
    }

    // ---- compute tile kt from cur buffer (skip if out of wave's window) ----
    const int ktb = kt * 64;
    if (ktb <= qw0 + 31 && ktb + 63 >= qw0 - 1023) {
      const unsigned short* kb = &smem[cur * 17920];
      const unsigned short* vb = kb + 8704;

      // QK^T
      f32x16 s0 = {}, s1 = {};
      const int arow = l31 * 136 + hi * 8;
#pragma unroll
      for (int ks8 = 0; ks8 < 8; ++ks8) {
        u32x4 a0 = *(const u32x4*)&kb[arow + ks8 * 16];
        u32x4 a1 = *(const u32x4*)&kb[arow + 32 * 136 + ks8 * 16];
        s0 = MFMA32(BC8(a0), qf[ks8], s0);
        s1 = MFMA32(BC8(a1), qf[ks8], s1);
      }

      // scale + mask
      const float scale = 0.08838834764831845f;
      float pv[32];
      const bool need_mask = !(ktb + 63 <= qw0 && ktb >= qw0 - 992);
      if (need_mask) {
#pragma unroll
        for (int r = 0; r < 16; ++r) {
          const int key0 = ktb + ((r & 3) + 8 * (r >> 2) + 4 * hi);
          const int key1 = key0 + 32;
          pv[r]      = (key0 <= qg && qg - key0 < 1024) ? s0[r] * scale : -1e30f;
          pv[16 + r] = (key1 <= qg && qg - key1 < 1024) ? s1[r] * scale : -1e30f;
        }
      } else {
#pragma unroll
        for (int r = 0; r < 16; ++r) {
          pv[r] = s0[r] * scale;
          pv[16 + r] = s1[r] * scale;
        }
      }

      // online softmax with defer-max (THR=8)
      float tm = -1e30f;
#pragma unroll
      for (int i = 0; i < 32; ++i) tm = fmaxf(tm, pv[i]);
      tm = fmaxf(tm, __shfl_xor(tm, 32, 64));
      if (__any(tm > m_run + 8.0f)) {
        const float mn = fmaxf(fmaxf(m_run, tm), -1e20f);
        const float scl = __expf(m_run - mn);
#pragma unroll
        for (int d = 0; d < 4; ++d) o_acc[d] *= scl;
        l_run *= scl;
        m_run = mn;
      }
      float lsum = 0.0f;
#pragma unroll
      for (int i = 0; i < 32; ++i) {
        pv[i] = __expf(pv[i] - m_run);
        lsum += pv[i];
      }
      l_run += lsum + __shfl_xor(lsum, 32, 64);

      // P -> bf16 fragments via cvt_pk + permlane32_swap (T12)
      u32x4 paf[4];
#pragma unroll
      for (int ks = 0; ks < 4; ++ks) {
        const int base = (ks >> 1) * 16 + (ks & 1) * 8;
        auto rA = __builtin_amdgcn_permlane32_swap(
            (int)cvtpk_bf16(pv[base + 0], pv[base + 1]),
            (int)cvtpk_bf16(pv[base + 4], pv[base + 5]), false, false);
        auto rB = __builtin_amdgcn_permlane32_swap(
            (int)cvtpk_bf16(pv[base + 2], pv[base + 3]),
            (int)cvtpk_bf16(pv[base + 6], pv[base + 7]), false, false);
        paf[ks][0] = (unsigned int)rA[0];
        paf[ks][1] = (unsigned int)rB[0];
        paf[ks][2] = (unsigned int)rA[1];
        paf[ks][3] = (unsigned int)rB[1];
      }

      // O^T += V^T * P^T
#pragma unroll
      for (int dblk = 0; dblk < 4; ++dblk) {
        const int vrow = (dblk * 32 + l31) * 72 + hi * 8;
#pragma unroll
        for (int ks = 0; ks < 4; ++ks) {
          u32x4 vf = *(const u32x4*)&vb[vrow + ks * 16];
          o_acc[dblk] = MFMA32(BC8(vf), BC8(paf[ks]), o_acc[dblk]);
        }
      }
    }

    __syncthreads();
  }

  // ---- epilogue: divide by l, stage O in LDS, store coalesced ----
  const float rl = 1.0f / l_run;
  unsigned short* ob = &smem[w * 4352];   // per-wave [32][136]
#pragma unroll
  for (int dblk = 0; dblk < 4; ++dblk)
#pragma unroll
    for (int rq = 0; rq < 4; ++rq) {
      u16x4 pk;
#pragma unroll
      for (int i = 0; i < 4; ++i) pk[i] = f2bf(o_acc[dblk][rq * 4 + i] * rl);
      *(u16x4*)&ob[l31 * 136 + dblk * 32 + rq * 8 + hi * 4] = pk;
    }
  __syncthreads();

  unsigned short* gout = aout + (tokbase + q0 + w * 32) * 4096 + h * 128;
#pragma unroll
  for (int r4 = 0; r4 < 8; ++r4) {
    const int row = r4 * 4 + (lane >> 4);
    u32x4 val = *(const u32x4*)&ob[row * 136 + (lane & 15) * 8];
    *(u32x4*)(gout + (size_t)row * 4096 + (lane & 15) * 8) = val;
  }
}

// ---------------------------------------------------------------------------
// launch
// ---------------------------------------------------------------------------
extern "C" void kernel_launch(void* const* d_in, const int* in_sizes, int n_in,
                              void* d_out, int out_size, void* d_ws, size_t ws_size,
                              hipStream_t stream) {
  (void)in_sizes; (void)n_in; (void)out_size; (void)ws_size;
  const float* hs   = (const float*)d_in[0];   // [2,2048,4096]
  const float* wqkv = (const float*)d_in[1];   // [4096,6144]
  const float* wo   = (const float*)d_in[2];   // [4096,4096]
  const int*   pos  = (const int*)d_in[3];     // [2048]
  float* out = (float*)d_out;                  // [2,2048,4096] fp32

  char* ws = (char*)d_ws;
  unsigned short* qkvb = (unsigned short*)ws;                // [4096][6144] bf16
  unsigned short* wT   = (unsigned short*)(ws + 50331648);   // weightT bf16
  unsigned short* hsb  = (unsigned short*)(ws + 100663296);  // [4096][4096] bf16

  cvt_t<<<dim3(6144 / 32, 4096 / 32), 256, 0, stream>>>(wqkv, wT, 4096, 6144);
  cvt_plain<<<16384, 256, 0, stream>>>(hs, hsb, 16777216);
  gemm_bt<0><<<dim3(32, 48), 256, 0, stream>>>(hsb, wT, qkvb, 4096, 6144, 4096);
  rope_kernel<<<40960, 256, 0, stream>>>(qkvb, pos);
  cvt_t<<<dim3(4096 / 32, 4096 / 32), 256, 0, stream>>>(wo, wT, 4096, 4096);
  attn_kernel<<<dim3(8, 32, 2), 512, 0, stream>>>(qkvb, hsb);
  gemm_bt<1><<<dim3(32, 32), 256, 0, stream>>>(hsb, wT, out, 4096, 4096, 4096);
}

// Round 3
// 535.961 us; speedup vs baseline: 1.5330x; 1.2165x over previous
//
#include <hip/hip_runtime.h>

// ---------------------------------------------------------------------------
// MixtralAttention on MI355X (gfx950)
// B=2, S=2048, HID=4096, NH=32, NKV=8, HD=128, WINDOW=1024, THETA=10000
// Stages: cvt(+T) -> GEMM1(qkv, 256^2 8-phase) -> RoPE -> flash attn
//         -> GEMM2(out, 256^2 8-phase)
// ---------------------------------------------------------------------------

typedef __attribute__((ext_vector_type(8))) short short8;       // bf16x8 frag
typedef __attribute__((ext_vector_type(4))) float f32x4;        // 16x16 acc
typedef __attribute__((ext_vector_type(16))) float f32x16;      // 32x32 acc
typedef __attribute__((ext_vector_type(4))) unsigned int u32x4; // 16B load
typedef __attribute__((ext_vector_type(4))) unsigned short u16x4;

__device__ __forceinline__ unsigned short f2bf(float f) {
  unsigned int u = __builtin_bit_cast(unsigned int, f);
  u = u + 0x7fffu + ((u >> 16) & 1u);   // round-to-nearest-even
  return (unsigned short)(u >> 16);
}
__device__ __forceinline__ float bf2f(unsigned short h) {
  unsigned int u = ((unsigned int)h) << 16;
  return __builtin_bit_cast(float, u);
}
__device__ __forceinline__ unsigned int cvtpk_bf16(float lo, float hi) {
  unsigned int r;
  asm("v_cvt_pk_bf16_f32 %0, %1, %2" : "=v"(r) : "v"(lo), "v"(hi));
  return r;
}

__device__ __forceinline__ void gload_lds16(const unsigned short* g, unsigned short* l) {
  __builtin_amdgcn_global_load_lds(
      (const __attribute__((address_space(1))) unsigned int*)g,
      (__attribute__((address_space(3))) unsigned int*)l, 16, 0, 0);
}

#define MFMA16(A, B, C) __builtin_amdgcn_mfma_f32_16x16x32_bf16((A), (B), (C), 0, 0, 0)
#define MFMA32(A, B, C) __builtin_amdgcn_mfma_f32_32x32x16_bf16((A), (B), (C), 0, 0, 0)
#define BC8(x) __builtin_bit_cast(short8, (x))

// ---------------------------------------------------------------------------
// fp32 -> bf16 plain convert
// ---------------------------------------------------------------------------
__global__ __launch_bounds__(256) void cvt_plain(const float* __restrict__ in,
                                                 unsigned short* __restrict__ out, int n) {
  const int i = (blockIdx.x * 256 + threadIdx.x) * 4;
  (void)n;
  f32x4 v = *(const f32x4*)(in + i);
  u16x4 o;
#pragma unroll
  for (int j = 0; j < 4; ++j) o[j] = f2bf(v[j]);
  *(u16x4*)(out + i) = o;
}

// ---------------------------------------------------------------------------
// fp32 [R][C] -> bf16 transposed [C][R]
// ---------------------------------------------------------------------------
__global__ __launch_bounds__(256) void cvt_t(const float* __restrict__ in,
                                             unsigned short* __restrict__ out,
                                             int R, int C) {
  __shared__ float t[32][33];
  const int c0 = blockIdx.x * 32, r0 = blockIdx.y * 32;
  const int tx = threadIdx.x & 31, ty = threadIdx.x >> 5;
#pragma unroll
  for (int i = 0; i < 4; ++i)
    t[ty + i * 8][tx] = in[(size_t)(r0 + ty + i * 8) * C + c0 + tx];
  __syncthreads();
#pragma unroll
  for (int i = 0; i < 4; ++i)
    out[(size_t)(c0 + ty + i * 8) * R + r0 + tx] = f2bf(t[tx][ty + i * 8]);
}

// ---------------------------------------------------------------------------
// GEMM: C[M,N] = A[M,K] * B^T[N,K]  -- 256x256 8-phase template (T2+T3+T4+T5)
// 512 threads = 8 waves (2Mx4N); per-wave 128x64 output (acc[8][4] 16x16).
// BK=64; LDS 2 x (A[256][64] + B[256][64]) bf16 = 128 KiB double buffer.
// Staging: global_load_lds w16, pre-swizzled global src; ds_read XOR-swizzled
//   (cb ^= (row&7)<<4) -> conflict-free b128 reads.
// Per K-tile 4 phases: {ds_read quadrant | issue 2 stage rounds | counted
//   vmcnt | barrier | lgkmcnt(0) | setprio(1) 16xMFMA setprio(0) | barrier}.
// Issue rounds per tile: 0-3 = B rows {0,64,128,192}, 4-7 = A rows
//   {0,128,64,192}. Waits: vmcnt(4)@P1 (tile t rounds 6,7), vmcnt(2)@P3
//   (tile t+1 rounds 0-5). Never drains in main loop.
// ---------------------------------------------------------------------------
template <int OUTF32>
__global__ __launch_bounds__(512, 2) void gemm256(const unsigned short* __restrict__ A,
                                                  const unsigned short* __restrict__ BT,
                                                  void* __restrict__ Cout,
                                                  int M, int N, int K) {
  __shared__ __align__(16) unsigned short lds[2][32768];  // [buf][A:16384 | B:16384]
  const int tid = threadIdx.x;
  const int lane = tid & 63;
  const int w = tid >> 6;          // wave 0..7
  const int wr = w >> 2;           // 0..1 (M)
  const int wc = w & 3;            // 0..3 (N)
  const int g = lane >> 4;
  const int l15 = lane & 15;
  const int m0 = blockIdx.x * 256;
  const int n0 = blockIdx.y * 256;

  // staging per-lane constants: lane covers row (l>>3), swizzled col
  const int lrow = lane >> 3;                 // 0..7
  const int lcol = ((lane & 7) ^ lrow) * 8;   // pre-swizzled source col (elems)
  const unsigned short* Asrc = A + (size_t)(m0 + w * 8 + lrow) * K + lcol;
  const unsigned short* Bsrc = BT + (size_t)(n0 + w * 8 + lrow) * K + lcol;

  f32x4 acc[8][4] = {};

  auto stage = [&](int buf, int t, int r) {
    const int rb = (r < 4) ? (r * 64) : ((r & 1) * 128 + ((r >> 1) & 1) * 64);
    const unsigned short* src = ((r >= 4) ? Asrc : Bsrc) + (size_t)rb * K + t * 64;
    unsigned short* dst = &lds[buf][((r >= 4) ? 0 : 16384) + (rb + w * 8) * 64];
    gload_lds16(src, dst);
  };
  auto rdA = [&](int buf, int mi, int ks) {
    const int row = wr * 128 + mi * 16 + l15;
    const int cb = (ks * 64 + g * 16) ^ ((l15 & 7) << 4);
    return *(const u32x4*)((const char*)&lds[buf][0] + row * 128 + cb);
  };
  auto rdB = [&](int buf, int ni, int ks) {
    const int row = wc * 64 + ni * 16 + l15;
    const int cb = (ks * 64 + g * 16) ^ ((l15 & 7) << 4);
    return *(const u32x4*)((const char*)&lds[buf][16384] + row * 128 + cb);
  };

  // prologue: stage tile 0 fully; wait rounds 0-5 landed
#pragma unroll
  for (int r = 0; r < 8; ++r) stage(0, 0, r);
  asm volatile("s_waitcnt vmcnt(2)" ::: "memory");
  __builtin_amdgcn_sched_barrier(0);
  __builtin_amdgcn_s_barrier();

  const int NT = K >> 6;
  for (int t = 0; t < NT; ++t) {
    const int cb_ = t & 1, nb_ = cb_ ^ 1;
    const bool pre = (t + 1 < NT);
    u32x4 bfr[4][2];

    // ---------------- P0 : mi 0,1 (+ all B frags) ----------------
    {
#pragma unroll
      for (int ni = 0; ni < 4; ++ni) {
        bfr[ni][0] = rdB(cb_, ni, 0);
        bfr[ni][1] = rdB(cb_, ni, 1);
      }
      u32x4 a00 = rdA(cb_, 0, 0), a01 = rdA(cb_, 0, 1);
      u32x4 a10 = rdA(cb_, 1, 0), a11 = rdA(cb_, 1, 1);
      if (pre) { stage(nb_, t + 1, 0); stage(nb_, t + 1, 1); }
      __builtin_amdgcn_sched_barrier(0);
      __builtin_amdgcn_s_barrier();
      asm volatile("s_waitcnt lgkmcnt(0)" ::: "memory");
      __builtin_amdgcn_sched_barrier(0);
      __builtin_amdgcn_s_setprio(1);
#pragma unroll
      for (int ni = 0; ni < 4; ++ni) {
        acc[0][ni] = MFMA16(BC8(a00), BC8(bfr[ni][0]), acc[0][ni]);
        acc[0][ni] = MFMA16(BC8(a01), BC8(bfr[ni][1]), acc[0][ni]);
        acc[1][ni] = MFMA16(BC8(a10), BC8(bfr[ni][0]), acc[1][ni]);
        acc[1][ni] = MFMA16(BC8(a11), BC8(bfr[ni][1]), acc[1][ni]);
      }
      __builtin_amdgcn_s_setprio(0);
      __builtin_amdgcn_sched_barrier(0);
      __builtin_amdgcn_s_barrier();
    }
    // ---------------- P1 : mi 2,3 ----------------
    {
      u32x4 a00 = rdA(cb_, 2, 0), a01 = rdA(cb_, 2, 1);
      u32x4 a10 = rdA(cb_, 3, 0), a11 = rdA(cb_, 3, 1);
      if (pre) {
        stage(nb_, t + 1, 2); stage(nb_, t + 1, 3);
        asm volatile("s_waitcnt vmcnt(4)" ::: "memory");   // t rounds 6,7 landed
      } else {
        asm volatile("s_waitcnt vmcnt(0)" ::: "memory");   // last tile: drain
      }
      __builtin_amdgcn_sched_barrier(0);
      __builtin_amdgcn_s_barrier();
      asm volatile("s_waitcnt lgkmcnt(0)" ::: "memory");
      __builtin_amdgcn_sched_barrier(0);
      __builtin_amdgcn_s_setprio(1);
#pragma unroll
      for (int ni = 0; ni < 4; ++ni) {
        acc[2][ni] = MFMA16(BC8(a00), BC8(bfr[ni][0]), acc[2][ni]);
        acc[2][ni] = MFMA16(BC8(a01), BC8(bfr[ni][1]), acc[2][ni]);
        acc[3][ni] = MFMA16(BC8(a10), BC8(bfr[ni][0]), acc[3][ni]);
        acc[3][ni] = MFMA16(BC8(a11), BC8(bfr[ni][1]), acc[3][ni]);
      }
      __builtin_amdgcn_s_setprio(0);
      __builtin_amdgcn_sched_barrier(0);
      __builtin_amdgcn_s_barrier();
    }
    // ---------------- P2 : mi 4,5 ----------------
    {
      u32x4 a00 = rdA(cb_, 4, 0), a01 = rdA(cb_, 4, 1);
      u32x4 a10 = rdA(cb_, 5, 0), a11 = rdA(cb_, 5, 1);
      if (pre) { stage(nb_, t + 1, 4); stage(nb_, t + 1, 5); }
      __builtin_amdgcn_sched_barrier(0);
      __builtin_amdgcn_s_barrier();
      asm volatile("s_waitcnt lgkmcnt(0)" ::: "memory");
      __builtin_amdgcn_sched_barrier(0);
      __builtin_amdgcn_s_setprio(1);
#pragma unroll
      for (int ni = 0; ni < 4; ++ni) {
        acc[4][ni] = MFMA16(BC8(a00), BC8(bfr[ni][0]), acc[4][ni]);
        acc[4][ni] = MFMA16(BC8(a01), BC8(bfr[ni][1]), acc[4][ni]);
        acc[5][ni] = MFMA16(BC8(a10), BC8(bfr[ni][0]), acc[5][ni]);
        acc[5][ni] = MFMA16(BC8(a11), BC8(bfr[ni][1]), acc[5][ni]);
      }
      __builtin_amdgcn_s_setprio(0);
      __builtin_amdgcn_sched_barrier(0);
      __builtin_amdgcn_s_barrier();
    }
    // ---------------- P3 : mi 6,7 ----------------
    {
      u32x4 a00 = rdA(cb_, 6, 0), a01 = rdA(cb_, 6, 1);
      u32x4 a10 = rdA(cb_, 7, 0), a11 = rdA(cb_, 7, 1);
      if (pre) {
        stage(nb_, t + 1, 6); stage(nb_, t + 1, 7);
        asm volatile("s_waitcnt vmcnt(2)" ::: "memory");   // t+1 rounds 0-5 landed
      }
      __builtin_amdgcn_sched_barrier(0);
      __builtin_amdgcn_s_barrier();
      asm volatile("s_waitcnt lgkmcnt(0)" ::: "memory");
      __builtin_amdgcn_sched_barrier(0);
      __builtin_amdgcn_s_setprio(1);
#pragma unroll
      for (int ni = 0; ni < 4; ++ni) {
        acc[6][ni] = MFMA16(BC8(a00), BC8(bfr[ni][0]), acc[6][ni]);
        acc[6][ni] = MFMA16(BC8(a01), BC8(bfr[ni][1]), acc[6][ni]);
        acc[7][ni] = MFMA16(BC8(a10), BC8(bfr[ni][0]), acc[7][ni]);
        acc[7][ni] = MFMA16(BC8(a11), BC8(bfr[ni][1]), acc[7][ni]);
      }
      __builtin_amdgcn_s_setprio(0);
      __builtin_amdgcn_sched_barrier(0);
      __builtin_amdgcn_s_barrier();
    }
  }

  // epilogue: C row = crow0 + mi*16 + g*4 + r, col = ccol0 + ni*16 + l15
  const int crow0 = m0 + wr * 128;
  const int ccol0 = n0 + wc * 64;
#pragma unroll
  for (int mi = 0; mi < 8; ++mi)
#pragma unroll
    for (int ni = 0; ni < 4; ++ni)
#pragma unroll
      for (int r = 0; r < 4; ++r) {
        const size_t idx =
            (size_t)(crow0 + mi * 16 + g * 4 + r) * N + (ccol0 + ni * 16 + l15);
        if constexpr (OUTF32) ((float*)Cout)[idx] = acc[mi][ni][r];
        else ((unsigned short*)Cout)[idx] = f2bf(acc[mi][ni][r]);
      }
}

// ---------------------------------------------------------------------------
// RoPE (NeoX) in-place on qkv bf16 [4096][6144]
// ---------------------------------------------------------------------------
__global__ __launch_bounds__(256) void rope_kernel(unsigned short* __restrict__ qkv,
                                                   const int* __restrict__ pos) {
  const int idx = blockIdx.x * 256 + threadIdx.x;
  const int d = idx & 63;
  const int hh = (idx >> 6) % 40;
  const int tok = idx / 2560;
  const int s = tok & 2047;
  const int off = (hh < 32) ? hh * 128 : 4096 + (hh - 32) * 128;
  unsigned short* p = qkv + (size_t)tok * 6144 + off + d;
  const float x1 = bf2f(p[0]);
  const float x2 = bf2f(p[64]);
  const float inv = exp2f(-(float)d * 0.2076205059304601f);
  const float ang = (float)pos[s] * inv;
  const float c = cosf(ang), sn = sinf(ang);
  p[0]  = f2bf(x1 * c - x2 * sn);
  p[64] = f2bf(x2 * c + x1 * sn);
}

// ---------------------------------------------------------------------------
// Flash attention, GQA, causal + sliding window 1024. (unchanged from r2)
// 8 waves x 32 q-rows (512 thr); KV tile 64, double-buffered LDS.
// ---------------------------------------------------------------------------
__global__ __launch_bounds__(512, 2) void attn_kernel(const unsigned short* __restrict__ qkv,
                                                      unsigned short* __restrict__ aout) {
  __shared__ __align__(16) unsigned short smem[35840];   // 2 buffers, 70 KiB

  const int tid = threadIdx.x;
  const int lane = tid & 63;
  const int w = tid >> 6;
  const int hi = lane >> 5;
  const int l31 = lane & 31;
  const int q0 = blockIdx.x * 256;
  const int h = blockIdx.y;
  const int b = blockIdx.z;
  const int kh = h >> 2;
  const size_t tokbase = (size_t)b * 2048;
  const int qw0 = q0 + w * 32;
  const int qg = qw0 + l31;

  short8 qf[8];
  {
    const unsigned short* qp = qkv + (tokbase + qg) * 6144 + h * 128;
#pragma unroll
    for (int ks8 = 0; ks8 < 8; ++ks8)
      qf[ks8] = BC8(*(const u32x4*)(qp + ks8 * 16 + hi * 8));
  }

  const int c0key = tid >> 4, c0col = tid & 15;
  const int c1key = (tid + 512) >> 4, c1col = tid & 15;

  u32x4 kreg[2], vreg[2];
  const unsigned short* kvK = qkv + tokbase * 6144 + 4096 + kh * 128;

  const int t0 = (q0 >= 1024 ? (q0 - 1023) >> 6 : 0);
  const int t1 = (q0 + 255) >> 6;

  {
    const unsigned short* kb = kvK + (size_t)(t0 * 64) * 6144;
    kreg[0] = *(const u32x4*)(kb + (size_t)c0key * 6144 + c0col * 8);
    kreg[1] = *(const u32x4*)(kb + (size_t)c1key * 6144 + c1col * 8);
    vreg[0] = *(const u32x4*)(kb + (size_t)c0key * 6144 + 1024 + c0col * 8);
    vreg[1] = *(const u32x4*)(kb + (size_t)c1key * 6144 + 1024 + c1col * 8);
  }

  float m_run = -1e30f, l_run = 0.0f;
  f32x16 o_acc[4] = {};

  for (int kt = t0; kt <= t1; ++kt) {
    const int cur = (kt - t0) & 1;
    unsigned short* kdst = &smem[(cur)*17920];
    unsigned short* vdst = kdst + 8704;

    if (kt == t0) {
      *(u32x4*)&kdst[c0key * 136 + c0col * 8] = kreg[0];
      *(u32x4*)&kdst[c1key * 136 + c1col * 8] = kreg[1];
#pragma unroll
      for (int e = 0; e < 8; ++e) {
        const int e0 = (e + c0col) & 7;
        const int e1 = (e + c1col) & 7;
        vdst[(c0col * 8 + e0) * 72 + c0key] =
            (unsigned short)(vreg[0][e0 >> 1] >> ((e0 & 1) * 16));
        vdst[(c1col * 8 + e1) * 72 + c1key] =
            (unsigned short)(vreg[1][e1 >> 1] >> ((e1 & 1) * 16));
      }
      if (kt < t1) {
        const unsigned short* kb = kvK + (size_t)((kt + 1) * 64) * 6144;
        kreg[0] = *(const u32x4*)(kb + (size_t)c0key * 6144 + c0col * 8);
        kreg[1] = *(const u32x4*)(kb + (size_t)c1key * 6144 + c1col * 8);
        vreg[0] = *(const u32x4*)(kb + (size_t)c0key * 6144 + 1024 + c0col * 8);
        vreg[1] = *(const u32x4*)(kb + (size_t)c1key * 6144 + 1024 + c1col * 8);
      }
      __syncthreads();
    }

    if (kt < t1) {
      unsigned short* kdn = &smem[(cur ^ 1) * 17920];
      unsigned short* vdn = kdn + 8704;
      *(u32x4*)&kdn[c0key * 136 + c0col * 8] = kreg[0];
      *(u32x4*)&kdn[c1key * 136 + c1col * 8] = kreg[1];
#pragma unroll
      for (int e = 0; e < 8; ++e) {
        const int e0 = (e + c0col) & 7;
        const int e1 = (e + c1col) & 7;
        vdn[(c0col * 8 + e0) * 72 + c0key] =
            (unsigned short)(vreg[0][e0 >> 1] >> ((e0 & 1) * 16));
        vdn[(c1col * 8 + e1) * 72 + c1key] =
            (unsigned short)(vreg[1][e1 >> 1] >> ((e1 & 1) * 16));
      }
      if (kt + 2 <= t1) {
        const unsigned short* kb = kvK + (size_t)((kt + 2) * 64) * 6144;
        kreg[0] = *(const u32x4*)(kb + (size_t)c0key * 6144 + c0col * 8);
        kreg[1] = *(const u32x4*)(kb + (size_t)c1key * 6144 + c1col * 8);
        vreg[0] = *(const u32x4*)(kb + (size_t)c0key * 6144 + 1024 + c0col * 8);
        vreg[1] = *(const u32x4*)(kb + (size_t)c1key * 6144 + 1024 + c1col * 8);
      }
    }

    const int ktb = kt * 64;
    if (ktb <= qw0 + 31 && ktb + 63 >= qw0 - 1023) {
      const unsigned short* kb = &smem[cur * 17920];
      const unsigned short* vb = kb + 8704;

      f32x16 s0 = {}, s1 = {};
      const int arow = l31 * 136 + hi * 8;
#pragma unroll
      for (int ks8 = 0; ks8 < 8; ++ks8) {
        u32x4 a0 = *(const u32x4*)&kb[arow + ks8 * 16];
        u32x4 a1 = *(const u32x4*)&kb[arow + 32 * 136 + ks8 * 16];
        s0 = MFMA32(BC8(a0), qf[ks8], s0);
        s1 = MFMA32(BC8(a1), qf[ks8], s1);
      }

      const float scale = 0.08838834764831845f;
      float pv[32];
      const bool need_mask = !(ktb + 63 <= qw0 && ktb >= qw0 - 992);
      if (need_mask) {
#pragma unroll
        for (int r = 0; r < 16; ++r) {
          const int key0 = ktb + ((r & 3) + 8 * (r >> 2) + 4 * hi);
          const int key1 = key0 + 32;
          pv[r]      = (key0 <= qg && qg - key0 < 1024) ? s0[r] * scale : -1e30f;
          pv[16 + r] = (key1 <= qg && qg - key1 < 1024) ? s1[r] * scale : -1e30f;
        }
      } else {
#pragma unroll
        for (int r = 0; r < 16; ++r) {
          pv[r] = s0[r] * scale;
          pv[16 + r] = s1[r] * scale;
        }
      }

      float tm = -1e30f;
#pragma unroll
      for (int i = 0; i < 32; ++i) tm = fmaxf(tm, pv[i]);
      tm = fmaxf(tm, __shfl_xor(tm, 32, 64));
      if (__any(tm > m_run + 8.0f)) {
        const float mn = fmaxf(fmaxf(m_run, tm), -1e20f);
        const float scl = __expf(m_run - mn);
#pragma unroll
        for (int d = 0; d < 4; ++d) o_acc[d] *= scl;
        l_run *= scl;
        m_run = mn;
      }
      float lsum = 0.0f;
#pragma unroll
      for (int i = 0; i < 32; ++i) {
        pv[i] = __expf(pv[i] - m_run);
        lsum += pv[i];
      }
      l_run += lsum + __shfl_xor(lsum, 32, 64);

      u32x4 paf[4];
#pragma unroll
      for (int ks = 0; ks < 4; ++ks) {
        const int base = (ks >> 1) * 16 + (ks & 1) * 8;
        auto rA = __builtin_amdgcn_permlane32_swap(
            (int)cvtpk_bf16(pv[base + 0], pv[base + 1]),
            (int)cvtpk_bf16(pv[base + 4], pv[base + 5]), false, false);
        auto rB = __builtin_amdgcn_permlane32_swap(
            (int)cvtpk_bf16(pv[base + 2], pv[base + 3]),
            (int)cvtpk_bf16(pv[base + 6], pv[base + 7]), false, false);
        paf[ks][0] = (unsigned int)rA[0];
        paf[ks][1] = (unsigned int)rB[0];
        paf[ks][2] = (unsigned int)rA[1];
        paf[ks][3] = (unsigned int)rB[1];
      }

#pragma unroll
      for (int dblk = 0; dblk < 4; ++dblk) {
        const int vrow = (dblk * 32 + l31) * 72 + hi * 8;
#pragma unroll
        for (int ks = 0; ks < 4; ++ks) {
          u32x4 vf = *(const u32x4*)&vb[vrow + ks * 16];
          o_acc[dblk] = MFMA32(BC8(vf), BC8(paf[ks]), o_acc[dblk]);
        }
      }
    }

    __syncthreads();
  }

  const float rl = 1.0f / l_run;
  unsigned short* ob = &smem[w * 4352];
#pragma unroll
  for (int dblk = 0; dblk < 4; ++dblk)
#pragma unroll
    for (int rq = 0; rq < 4; ++rq) {
      u16x4 pk;
#pragma unroll
      for (int i = 0; i < 4; ++i) pk[i] = f2bf(o_acc[dblk][rq * 4 + i] * rl);
      *(u16x4*)&ob[l31 * 136 + dblk * 32 + rq * 8 + hi * 4] = pk;
    }
  __syncthreads();

  unsigned short* gout = aout + (tokbase + q0 + w * 32) * 4096 + h * 128;
#pragma unroll
  for (int r4 = 0; r4 < 8; ++r4) {
    const int row = r4 * 4 + (lane >> 4);
    u32x4 val = *(const u32x4*)&ob[row * 136 + (lane & 15) * 8];
    *(u32x4*)(gout + (size_t)row * 4096 + (lane & 15) * 8) = val;
  }
}

// ---------------------------------------------------------------------------
// launch
// ---------------------------------------------------------------------------
extern "C" void kernel_launch(void* const* d_in, const int* in_sizes, int n_in,
                              void* d_out, int out_size, void* d_ws, size_t ws_size,
                              hipStream_t stream) {
  (void)in_sizes; (void)n_in; (void)out_size; (void)ws_size;
  const float* hs   = (const float*)d_in[0];   // [2,2048,4096]
  const float* wqkv = (const float*)d_in[1];   // [4096,6144]
  const float* wo   = (const float*)d_in[2];   // [4096,4096]
  const int*   pos  = (const int*)d_in[3];     // [2048]
  float* out = (float*)d_out;                  // [2,2048,4096] fp32

  char* ws = (char*)d_ws;
  unsigned short* qkvb = (unsigned short*)ws;                // [4096][6144] bf16
  unsigned short* wT   = (unsigned short*)(ws + 50331648);   // weightT bf16
  unsigned short* hsb  = (unsigned short*)(ws + 100663296);  // [4096][4096] bf16

  cvt_t<<<dim3(6144 / 32, 4096 / 32), 256, 0, stream>>>(wqkv, wT, 4096, 6144);
  cvt_plain<<<16384, 256, 0, stream>>>(hs, hsb, 16777216);
  gemm256<0><<<dim3(16, 24), 512, 0, stream>>>(hsb, wT, qkvb, 4096, 6144, 4096);
  rope_kernel<<<40960, 256, 0, stream>>>(qkvb, pos);
  cvt_t<<<dim3(4096 / 32, 4096 / 32), 256, 0, stream>>>(wo, wT, 4096, 4096);
  attn_kernel<<<dim3(8, 32, 2), 512, 0, stream>>>(qkvb, hsb);
  gemm256<1><<<dim3(16, 16), 512, 0, stream>>>(hsb, wT, out, 4096, 4096, 4096);
}

// Round 4
// 499.538 us; speedup vs baseline: 1.6448x; 1.0729x over previous
//
#include <hip/hip_runtime.h>

// ---------------------------------------------------------------------------
// MixtralAttention on MI355X (gfx950)
// B=2, S=2048, HID=4096, NH=32, NKV=8, HD=128, WINDOW=1024, THETA=10000
// Stages: cvt(+T) -> GEMM1(qkv, 256x192 8-phase, grid=512=2.0 waves)
//         -> RoPE -> flash attn -> GEMM2(out, 256x256 8-phase, grid=256)
// Both GEMMs: T1 XCD swizzle + T2 LDS XOR swizzle + T3/T4 counted vmcnt + T5.
// ---------------------------------------------------------------------------

typedef __attribute__((ext_vector_type(8))) short short8;       // bf16x8 frag
typedef __attribute__((ext_vector_type(4))) float f32x4;        // 16x16 acc
typedef __attribute__((ext_vector_type(16))) float f32x16;      // 32x32 acc
typedef __attribute__((ext_vector_type(4))) unsigned int u32x4; // 16B load
typedef __attribute__((ext_vector_type(4))) unsigned short u16x4;

__device__ __forceinline__ unsigned short f2bf(float f) {
  unsigned int u = __builtin_bit_cast(unsigned int, f);
  u = u + 0x7fffu + ((u >> 16) & 1u);   // round-to-nearest-even
  return (unsigned short)(u >> 16);
}
__device__ __forceinline__ float bf2f(unsigned short h) {
  unsigned int u = ((unsigned int)h) << 16;
  return __builtin_bit_cast(float, u);
}
__device__ __forceinline__ unsigned int cvtpk_bf16(float lo, float hi) {
  unsigned int r;
  asm("v_cvt_pk_bf16_f32 %0, %1, %2" : "=v"(r) : "v"(lo), "v"(hi));
  return r;
}

__device__ __forceinline__ void gload_lds16(const unsigned short* g, unsigned short* l) {
  __builtin_amdgcn_global_load_lds(
      (const __attribute__((address_space(1))) unsigned int*)g,
      (__attribute__((address_space(3))) unsigned int*)l, 16, 0, 0);
}

#define MFMA16(A, B, C) __builtin_amdgcn_mfma_f32_16x16x32_bf16((A), (B), (C), 0, 0, 0)
#define MFMA32(A, B, C) __builtin_amdgcn_mfma_f32_32x32x16_bf16((A), (B), (C), 0, 0, 0)
#define BC8(x) __builtin_bit_cast(short8, (x))

// ---------------------------------------------------------------------------
// fp32 -> bf16 plain convert
// ---------------------------------------------------------------------------
__global__ __launch_bounds__(256) void cvt_plain(const float* __restrict__ in,
                                                 unsigned short* __restrict__ out, int n) {
  const int i = (blockIdx.x * 256 + threadIdx.x) * 4;
  (void)n;
  f32x4 v = *(const f32x4*)(in + i);
  u16x4 o;
#pragma unroll
  for (int j = 0; j < 4; ++j) o[j] = f2bf(v[j]);
  *(u16x4*)(out + i) = o;
}

// ---------------------------------------------------------------------------
// fp32 [R][C] -> bf16 transposed [C][R]
// ---------------------------------------------------------------------------
__global__ __launch_bounds__(256) void cvt_t(const float* __restrict__ in,
                                             unsigned short* __restrict__ out,
                                             int R, int C) {
  __shared__ float t[32][33];
  const int c0 = blockIdx.x * 32, r0 = blockIdx.y * 32;
  const int tx = threadIdx.x & 31, ty = threadIdx.x >> 5;
#pragma unroll
  for (int i = 0; i < 4; ++i)
    t[ty + i * 8][tx] = in[(size_t)(r0 + ty + i * 8) * C + c0 + tx];
  __syncthreads();
#pragma unroll
  for (int i = 0; i < 4; ++i)
    out[(size_t)(c0 + ty + i * 8) * R + r0 + tx] = f2bf(t[tx][ty + i * 8]);
}

// ---------------------------------------------------------------------------
// GEMM: C[M,N] = A[M,K] * B^T[N,K]  -- 8-phase template (T1+T2+T3+T4+T5)
// Tile 256 x (NIF*64); 512 threads = 8 waves (2M x 4N); per-wave 128 x NIF*16.
// BK=64; LDS 2 x (A[256][64] + B[NIF*64][64]) bf16.
// Staging rounds/tile NR=NIF+4: 0..NIF-1 = B rows r*64; NIF+j = A rows
//   {0,128,64,192}[j]. Issue 2/phase (P3 issues NR-6). Waits: vmcnt(4)@P1
//   (tile t's last 2 A rounds landed), vmcnt(2)@P3 (t+1 rounds 0..NR-3
//   landed = exactly what next P0/P1 consume). Never drains in main loop.
// Grid: 1D, bijective XCD swizzle (nwg%8==0), M-fastest within XCD chunk
//   so consecutive blocks share the B panel (fits 4MiB XCD L2).
// ---------------------------------------------------------------------------
template <int NIF, int OUTF32>
__global__ __launch_bounds__(512, 2) void gemm256(const unsigned short* __restrict__ A,
                                                  const unsigned short* __restrict__ BT,
                                                  void* __restrict__ Cout,
                                                  int M, int N, int K) {
  constexpr int BUFE = 16384 + NIF * 4096;   // elems per dbuf half
  constexpr int NR = NIF + 4;
  __shared__ __align__(16) unsigned short lds[2][BUFE];
  const int tid = threadIdx.x;
  const int lane = tid & 63;
  const int w = tid >> 6;          // wave 0..7
  const int wr = w >> 2;           // 0..1 (M)
  const int wc = w & 3;            // 0..3 (N)
  const int g = lane >> 4;
  const int l15 = lane & 15;

  // T1: bijective XCD swizzle (gridDim.x % 8 == 0), then M-fastest decompose
  const int nwg = gridDim.x;
  const int cpx = nwg >> 3;
  const int bid = blockIdx.x;
  const int swz = (bid & 7) * cpx + (bid >> 3);
  const int MT = M >> 8;
  const int m0 = (swz % MT) * 256;
  const int n0 = (swz / MT) * (NIF * 64);

  // staging per-lane constants: lane covers row (l>>3), pre-swizzled col
  const int lrow = lane >> 3;                 // 0..7
  const int lcol = ((lane & 7) ^ lrow) * 8;   // pre-swizzled source col (elems)
  const unsigned short* Asrc = A + (size_t)(m0 + w * 8 + lrow) * K + lcol;
  const unsigned short* Bsrc = BT + (size_t)(n0 + w * 8 + lrow) * K + lcol;

  f32x4 acc[8][NIF] = {};

  auto stage = [&](int buf, int t, int r) {
    if (r < NIF) {
      const int rb = r * 64;
      gload_lds16(Bsrc + (size_t)rb * K + t * 64,
                  &lds[buf][16384 + (rb + w * 8) * 64]);
    } else {
      const int j = r - NIF;
      const int rb = (j & 1) * 128 + ((j >> 1) & 1) * 64;
      gload_lds16(Asrc + (size_t)rb * K + t * 64,
                  &lds[buf][(rb + w * 8) * 64]);
    }
  };
  auto rdA = [&](int buf, int mi, int ks) {
    const int row = wr * 128 + mi * 16 + l15;
    const int cb = (ks * 64 + g * 16) ^ ((l15 & 7) << 4);
    return *(const u32x4*)((const char*)&lds[buf][0] + row * 128 + cb);
  };
  auto rdB = [&](int buf, int ni, int ks) {
    const int row = wc * (NIF * 16) + ni * 16 + l15;
    const int cb = (ks * 64 + g * 16) ^ ((l15 & 7) << 4);
    return *(const u32x4*)((const char*)&lds[buf][0] + 32768 + row * 128 + cb);
  };

  // prologue: stage tile 0 fully; wait rounds 0..NR-3 landed
#pragma unroll
  for (int r = 0; r < NR; ++r) stage(0, 0, r);
  asm volatile("s_waitcnt vmcnt(2)" ::: "memory");
  __builtin_amdgcn_sched_barrier(0);
  __builtin_amdgcn_s_barrier();

  const int NT = K >> 6;
  for (int t = 0; t < NT; ++t) {
    const int cb_ = t & 1, nb_ = cb_ ^ 1;
    const bool pre = (t + 1 < NT);
    u32x4 bfr[NIF][2];

    // ---------------- P0 : mi 0,1 (+ all B frags) ----------------
    {
#pragma unroll
      for (int ni = 0; ni < NIF; ++ni) {
        bfr[ni][0] = rdB(cb_, ni, 0);
        bfr[ni][1] = rdB(cb_, ni, 1);
      }
      u32x4 a00 = rdA(cb_, 0, 0), a01 = rdA(cb_, 0, 1);
      u32x4 a10 = rdA(cb_, 1, 0), a11 = rdA(cb_, 1, 1);
      if (pre) { stage(nb_, t + 1, 0); stage(nb_, t + 1, 1); }
      __builtin_amdgcn_sched_barrier(0);
      __builtin_amdgcn_s_barrier();
      asm volatile("s_waitcnt lgkmcnt(0)" ::: "memory");
      __builtin_amdgcn_sched_barrier(0);
      __builtin_amdgcn_s_setprio(1);
#pragma unroll
      for (int ni = 0; ni < NIF; ++ni) {
        acc[0][ni] = MFMA16(BC8(a00), BC8(bfr[ni][0]), acc[0][ni]);
        acc[0][ni] = MFMA16(BC8(a01), BC8(bfr[ni][1]), acc[0][ni]);
        acc[1][ni] = MFMA16(BC8(a10), BC8(bfr[ni][0]), acc[1][ni]);
        acc[1][ni] = MFMA16(BC8(a11), BC8(bfr[ni][1]), acc[1][ni]);
      }
      __builtin_amdgcn_s_setprio(0);
      __builtin_amdgcn_sched_barrier(0);
      __builtin_amdgcn_s_barrier();
    }
    // ---------------- P1 : mi 2,3 ----------------
    {
      u32x4 a00 = rdA(cb_, 2, 0), a01 = rdA(cb_, 2, 1);
      u32x4 a10 = rdA(cb_, 3, 0), a11 = rdA(cb_, 3, 1);
      if (pre) {
        stage(nb_, t + 1, 2); stage(nb_, t + 1, 3);
        asm volatile("s_waitcnt vmcnt(4)" ::: "memory");   // t's A rounds landed
      } else {
        asm volatile("s_waitcnt vmcnt(0)" ::: "memory");   // last tile: drain
      }
      __builtin_amdgcn_sched_barrier(0);
      __builtin_amdgcn_s_barrier();
      asm volatile("s_waitcnt lgkmcnt(0)" ::: "memory");
      __builtin_amdgcn_sched_barrier(0);
      __builtin_amdgcn_s_setprio(1);
#pragma unroll
      for (int ni = 0; ni < NIF; ++ni) {
        acc[2][ni] = MFMA16(BC8(a00), BC8(bfr[ni][0]), acc[2][ni]);
        acc[2][ni] = MFMA16(BC8(a01), BC8(bfr[ni][1]), acc[2][ni]);
        acc[3][ni] = MFMA16(BC8(a10), BC8(bfr[ni][0]), acc[3][ni]);
        acc[3][ni] = MFMA16(BC8(a11), BC8(bfr[ni][1]), acc[3][ni]);
      }
      __builtin_amdgcn_s_setprio(0);
      __builtin_amdgcn_sched_barrier(0);
      __builtin_amdgcn_s_barrier();
    }
    // ---------------- P2 : mi 4,5 ----------------
    {
      u32x4 a00 = rdA(cb_, 4, 0), a01 = rdA(cb_, 4, 1);
      u32x4 a10 = rdA(cb_, 5, 0), a11 = rdA(cb_, 5, 1);
      if (pre) { stage(nb_, t + 1, 4); stage(nb_, t + 1, 5); }
      __builtin_amdgcn_sched_barrier(0);
      __builtin_amdgcn_s_barrier();
      asm volatile("s_waitcnt lgkmcnt(0)" ::: "memory");
      __builtin_amdgcn_sched_barrier(0);
      __builtin_amdgcn_s_setprio(1);
#pragma unroll
      for (int ni = 0; ni < NIF; ++ni) {
        acc[4][ni] = MFMA16(BC8(a00), BC8(bfr[ni][0]), acc[4][ni]);
        acc[4][ni] = MFMA16(BC8(a01), BC8(bfr[ni][1]), acc[4][ni]);
        acc[5][ni] = MFMA16(BC8(a10), BC8(bfr[ni][0]), acc[5][ni]);
        acc[5][ni] = MFMA16(BC8(a11), BC8(bfr[ni][1]), acc[5][ni]);
      }
      __builtin_amdgcn_s_setprio(0);
      __builtin_amdgcn_sched_barrier(0);
      __builtin_amdgcn_s_barrier();
    }
    // ---------------- P3 : mi 6,7 ----------------
    {
      u32x4 a00 = rdA(cb_, 6, 0), a01 = rdA(cb_, 6, 1);
      u32x4 a10 = rdA(cb_, 7, 0), a11 = rdA(cb_, 7, 1);
      if (pre) {
        stage(nb_, t + 1, 6);
        if (NR == 8) stage(nb_, t + 1, 7);
        asm volatile("s_waitcnt vmcnt(2)" ::: "memory");   // t+1 rounds 0..NR-3
      }
      __builtin_amdgcn_sched_barrier(0);
      __builtin_amdgcn_s_barrier();
      asm volatile("s_waitcnt lgkmcnt(0)" ::: "memory");
      __builtin_amdgcn_sched_barrier(0);
      __builtin_amdgcn_s_setprio(1);
#pragma unroll
      for (int ni = 0; ni < NIF; ++ni) {
        acc[6][ni] = MFMA16(BC8(a00), BC8(bfr[ni][0]), acc[6][ni]);
        acc[6][ni] = MFMA16(BC8(a01), BC8(bfr[ni][1]), acc[6][ni]);
        acc[7][ni] = MFMA16(BC8(a10), BC8(bfr[ni][0]), acc[7][ni]);
        acc[7][ni] = MFMA16(BC8(a11), BC8(bfr[ni][1]), acc[7][ni]);
      }
      __builtin_amdgcn_s_setprio(0);
      __builtin_amdgcn_sched_barrier(0);
      __builtin_amdgcn_s_barrier();
    }
  }

  // epilogue: C row = crow0 + mi*16 + g*4 + r, col = ccol0 + ni*16 + l15
  const int crow0 = m0 + wr * 128;
  const int ccol0 = n0 + wc * (NIF * 16);
#pragma unroll
  for (int mi = 0; mi < 8; ++mi)
#pragma unroll
    for (int ni = 0; ni < NIF; ++ni)
#pragma unroll
      for (int r = 0; r < 4; ++r) {
        const size_t idx =
            (size_t)(crow0 + mi * 16 + g * 4 + r) * N + (ccol0 + ni * 16 + l15);
        if constexpr (OUTF32) ((float*)Cout)[idx] = acc[mi][ni][r];
        else ((unsigned short*)Cout)[idx] = f2bf(acc[mi][ni][r]);
      }
}

// ---------------------------------------------------------------------------
// RoPE (NeoX) in-place on qkv bf16 [4096][6144]
// ---------------------------------------------------------------------------
__global__ __launch_bounds__(256) void rope_kernel(unsigned short* __restrict__ qkv,
                                                   const int* __restrict__ pos) {
  const int idx = blockIdx.x * 256 + threadIdx.x;
  const int d = idx & 63;
  const int hh = (idx >> 6) % 40;
  const int tok = idx / 2560;
  const int s = tok & 2047;
  const int off = (hh < 32) ? hh * 128 : 4096 + (hh - 32) * 128;
  unsigned short* p = qkv + (size_t)tok * 6144 + off + d;
  const float x1 = bf2f(p[0]);
  const float x2 = bf2f(p[64]);
  const float inv = exp2f(-(float)d * 0.2076205059304601f);
  const float ang = (float)pos[s] * inv;
  const float c = cosf(ang), sn = sinf(ang);
  p[0]  = f2bf(x1 * c - x2 * sn);
  p[64] = f2bf(x2 * c + x1 * sn);
}

// ---------------------------------------------------------------------------
// Flash attention, GQA, causal + sliding window 1024. (unchanged from r3)
// 8 waves x 32 q-rows (512 thr); KV tile 64, double-buffered LDS.
// ---------------------------------------------------------------------------
__global__ __launch_bounds__(512, 2) void attn_kernel(const unsigned short* __restrict__ qkv,
                                                      unsigned short* __restrict__ aout) {
  __shared__ __align__(16) unsigned short smem[35840];   // 2 buffers, 70 KiB

  const int tid = threadIdx.x;
  const int lane = tid & 63;
  const int w = tid >> 6;
  const int hi = lane >> 5;
  const int l31 = lane & 31;
  const int q0 = blockIdx.x * 256;
  const int h = blockIdx.y;
  const int b = blockIdx.z;
  const int kh = h >> 2;
  const size_t tokbase = (size_t)b * 2048;
  const int qw0 = q0 + w * 32;
  const int qg = qw0 + l31;

  short8 qf[8];
  {
    const unsigned short* qp = qkv + (tokbase + qg) * 6144 + h * 128;
#pragma unroll
    for (int ks8 = 0; ks8 < 8; ++ks8)
      qf[ks8] = BC8(*(const u32x4*)(qp + ks8 * 16 + hi * 8));
  }

  const int c0key = tid >> 4, c0col = tid & 15;
  const int c1key = (tid + 512) >> 4, c1col = tid & 15;

  u32x4 kreg[2], vreg[2];
  const unsigned short* kvK = qkv + tokbase * 6144 + 4096 + kh * 128;

  const int t0 = (q0 >= 1024 ? (q0 - 1023) >> 6 : 0);
  const int t1 = (q0 + 255) >> 6;

  {
    const unsigned short* kb = kvK + (size_t)(t0 * 64) * 6144;
    kreg[0] = *(const u32x4*)(kb + (size_t)c0key * 6144 + c0col * 8);
    kreg[1] = *(const u32x4*)(kb + (size_t)c1key * 6144 + c1col * 8);
    vreg[0] = *(const u32x4*)(kb + (size_t)c0key * 6144 + 1024 + c0col * 8);
    vreg[1] = *(const u32x4*)(kb + (size_t)c1key * 6144 + 1024 + c1col * 8);
  }

  float m_run = -1e30f, l_run = 0.0f;
  f32x16 o_acc[4] = {};

  for (int kt = t0; kt <= t1; ++kt) {
    const int cur = (kt - t0) & 1;
    unsigned short* kdst = &smem[(cur)*17920];
    unsigned short* vdst = kdst + 8704;

    if (kt == t0) {
      *(u32x4*)&kdst[c0key * 136 + c0col * 8] = kreg[0];
      *(u32x4*)&kdst[c1key * 136 + c1col * 8] = kreg[1];
#pragma unroll
      for (int e = 0; e < 8; ++e) {
        const int e0 = (e + c0col) & 7;
        const int e1 = (e + c1col) & 7;
        vdst[(c0col * 8 + e0) * 72 + c0key] =
            (unsigned short)(vreg[0][e0 >> 1] >> ((e0 & 1) * 16));
        vdst[(c1col * 8 + e1) * 72 + c1key] =
            (unsigned short)(vreg[1][e1 >> 1] >> ((e1 & 1) * 16));
      }
      if (kt < t1) {
        const unsigned short* kb = kvK + (size_t)((kt + 1) * 64) * 6144;
        kreg[0] = *(const u32x4*)(kb + (size_t)c0key * 6144 + c0col * 8);
        kreg[1] = *(const u32x4*)(kb + (size_t)c1key * 6144 + c1col * 8);
        vreg[0] = *(const u32x4*)(kb + (size_t)c0key * 6144 + 1024 + c0col * 8);
        vreg[1] = *(const u32x4*)(kb + (size_t)c1key * 6144 + 1024 + c1col * 8);
      }
      __syncthreads();
    }

    if (kt < t1) {
      unsigned short* kdn = &smem[(cur ^ 1) * 17920];
      unsigned short* vdn = kdn + 8704;
      *(u32x4*)&kdn[c0key * 136 + c0col * 8] = kreg[0];
      *(u32x4*)&kdn[c1key * 136 + c1col * 8] = kreg[1];
#pragma unroll
      for (int e = 0; e < 8; ++e) {
        const int e0 = (e + c0col) & 7;
        const int e1 = (e + c1col) & 7;
        vdn[(c0col * 8 + e0) * 72 + c0key] =
            (unsigned short)(vreg[0][e0 >> 1] >> ((e0 & 1) * 16));
        vdn[(c1col * 8 + e1) * 72 + c1key] =
            (unsigned short)(vreg[1][e1 >> 1] >> ((e1 & 1) * 16));
      }
      if (kt + 2 <= t1) {
        const unsigned short* kb = kvK + (size_t)((kt + 2) * 64) * 6144;
        kreg[0] = *(const u32x4*)(kb + (size_t)c0key * 6144 + c0col * 8);
        kreg[1] = *(const u32x4*)(kb + (size_t)c1key * 6144 + c1col * 8);
        vreg[0] = *(const u32x4*)(kb + (size_t)c0key * 6144 + 1024 + c0col * 8);
        vreg[1] = *(const u32x4*)(kb + (size_t)c1key * 6144 + 1024 + c1col * 8);
      }
    }

    const int ktb = kt * 64;
    if (ktb <= qw0 + 31 && ktb + 63 >= qw0 - 1023) {
      const unsigned short* kb = &smem[cur * 17920];
      const unsigned short* vb = kb + 8704;

      f32x16 s0 = {}, s1 = {};
      const int arow = l31 * 136 + hi * 8;
#pragma unroll
      for (int ks8 = 0; ks8 < 8; ++ks8) {
        u32x4 a0 = *(const u32x4*)&kb[arow + ks8 * 16];
        u32x4 a1 = *(const u32x4*)&kb[arow + 32 * 136 + ks8 * 16];
        s0 = MFMA32(BC8(a0), qf[ks8], s0);
        s1 = MFMA32(BC8(a1), qf[ks8], s1);
      }

      const float scale = 0.08838834764831845f;
      float pv[32];
      const bool need_mask = !(ktb + 63 <= qw0 && ktb >= qw0 - 992);
      if (need_mask) {
#pragma unroll
        for (int r = 0; r < 16; ++r) {
          const int key0 = ktb + ((r & 3) + 8 * (r >> 2) + 4 * hi);
          const int key1 = key0 + 32;
          pv[r]      = (key0 <= qg && qg - key0 < 1024) ? s0[r] * scale : -1e30f;
          pv[16 + r] = (key1 <= qg && qg - key1 < 1024) ? s1[r] * scale : -1e30f;
        }
      } else {
#pragma unroll
        for (int r = 0; r < 16; ++r) {
          pv[r] = s0[r] * scale;
          pv[16 + r] = s1[r] * scale;
        }
      }

      float tm = -1e30f;
#pragma unroll
      for (int i = 0; i < 32; ++i) tm = fmaxf(tm, pv[i]);
      tm = fmaxf(tm, __shfl_xor(tm, 32, 64));
      if (__any(tm > m_run + 8.0f)) {
        const float mn = fmaxf(fmaxf(m_run, tm), -1e20f);
        const float scl = __expf(m_run - mn);
#pragma unroll
        for (int d = 0; d < 4; ++d) o_acc[d] *= scl;
        l_run *= scl;
        m_run = mn;
      }
      float lsum = 0.0f;
#pragma unroll
      for (int i = 0; i < 32; ++i) {
        pv[i] = __expf(pv[i] - m_run);
        lsum += pv[i];
      }
      l_run += lsum + __shfl_xor(lsum, 32, 64);

      u32x4 paf[4];
#pragma unroll
      for (int ks = 0; ks < 4; ++ks) {
        const int base = (ks >> 1) * 16 + (ks & 1) * 8;
        auto rA = __builtin_amdgcn_permlane32_swap(
            (int)cvtpk_bf16(pv[base + 0], pv[base + 1]),
            (int)cvtpk_bf16(pv[base + 4], pv[base + 5]), false, false);
        auto rB = __builtin_amdgcn_permlane32_swap(
            (int)cvtpk_bf16(pv[base + 2], pv[base + 3]),
            (int)cvtpk_bf16(pv[base + 6], pv[base + 7]), false, false);
        paf[ks][0] = (unsigned int)rA[0];
        paf[ks][1] = (unsigned int)rB[0];
        paf[ks][2] = (unsigned int)rA[1];
        paf[ks][3] = (unsigned int)rB[1];
      }

#pragma unroll
      for (int dblk = 0; dblk < 4; ++dblk) {
        const int vrow = (dblk * 32 + l31) * 72 + hi * 8;
#pragma unroll
        for (int ks = 0; ks < 4; ++ks) {
          u32x4 vf = *(const u32x4*)&vb[vrow + ks * 16];
          o_acc[dblk] = MFMA32(BC8(vf), BC8(paf[ks]), o_acc[dblk]);
        }
      }
    }

    __syncthreads();
  }

  const float rl = 1.0f / l_run;
  unsigned short* ob = &smem[w * 4352];
#pragma unroll
  for (int dblk = 0; dblk < 4; ++dblk)
#pragma unroll
    for (int rq = 0; rq < 4; ++rq) {
      u16x4 pk;
#pragma unroll
      for (int i = 0; i < 4; ++i) pk[i] = f2bf(o_acc[dblk][rq * 4 + i] * rl);
      *(u16x4*)&ob[l31 * 136 + dblk * 32 + rq * 8 + hi * 4] = pk;
    }
  __syncthreads();

  unsigned short* gout = aout + (tokbase + q0 + w * 32) * 4096 + h * 128;
#pragma unroll
  for (int r4 = 0; r4 < 8; ++r4) {
    const int row = r4 * 4 + (lane >> 4);
    u32x4 val = *(const u32x4*)&ob[row * 136 + (lane & 15) * 8];
    *(u32x4*)(gout + (size_t)row * 4096 + (lane & 15) * 8) = val;
  }
}

// ---------------------------------------------------------------------------
// launch
// ---------------------------------------------------------------------------
extern "C" void kernel_launch(void* const* d_in, const int* in_sizes, int n_in,
                              void* d_out, int out_size, void* d_ws, size_t ws_size,
                              hipStream_t stream) {
  (void)in_sizes; (void)n_in; (void)out_size; (void)ws_size;
  const float* hs   = (const float*)d_in[0];   // [2,2048,4096]
  const float* wqkv = (const float*)d_in[1];   // [4096,6144]
  const float* wo   = (const float*)d_in[2];   // [4096,4096]
  const int*   pos  = (const int*)d_in[3];     // [2048]
  float* out = (float*)d_out;                  // [2,2048,4096] fp32

  char* ws = (char*)d_ws;
  unsigned short* qkvb = (unsigned short*)ws;                // [4096][6144] bf16
  unsigned short* wT   = (unsigned short*)(ws + 50331648);   // weightT bf16
  unsigned short* hsb  = (unsigned short*)(ws + 100663296);  // [4096][4096] bf16

  cvt_t<<<dim3(6144 / 32, 4096 / 32), 256, 0, stream>>>(wqkv, wT, 4096, 6144);
  cvt_plain<<<16384, 256, 0, stream>>>(hs, hsb, 16777216);
  // GEMM1: tile 256x192 -> grid 16*32 = 512 blocks = exactly 2.0 CU-waves
  gemm256<3, 0><<<512, 512, 0, stream>>>(hsb, wT, qkvb, 4096, 6144, 4096);
  rope_kernel<<<40960, 256, 0, stream>>>(qkvb, pos);
  cvt_t<<<dim3(4096 / 32, 4096 / 32), 256, 0, stream>>>(wo, wT, 4096, 4096);
  attn_kernel<<<dim3(8, 32, 2), 512, 0, stream>>>(qkvb, hsb);
  // GEMM2: tile 256x256 -> grid 16*16 = 256 blocks = exactly 1.0 CU-wave
  gemm256<4, 1><<<256, 512, 0, stream>>>(hsb, wT, out, 4096, 4096, 4096);
}